// Round 14
// baseline (165.694 us; speedup 1.0000x reference)
//
#include <hip/hip_runtime.h>
#include <math.h>

#define Bn 32
#define Nn 2000
#define En 32000
#define Vn 100000
#define Dn 128
#define Rn 39
#define Kn 8

#define SUBS 8
#define NPS (Nn / SUBS)   // 250 src nodes per sub-block
#define GW 16             // gather waves per ag block (SUBS*GW = 128 chunks/graph)
#define WPG (SUBS * GW)
#define EQ (En / 4)       // 8000 edge-quads per graph
#define TPB 1024

// Workspace layout (no aliasing):
//   [ 0)          : inv     float[B*E]          =  4,096,000
//   [ 4,096,000)  : partial float[B*WPG*9*128]  = 18,874,368
//   [22,970,368)  : gmat    float[B*9*128]      =    147,456
//   [23,117,824)  : ticket  int[B]              =        128
//
// 3 dispatches (R12 refit: ~20-25us fixed cost per dispatch dominates; the
// lever is dispatch count, but post-ticket tails must be tiny — R9 lesson).
// blockIdx.x = graph everywhere -> XCD affinity (R2 evidence: 9x fetch cut).

// K1: fused cnt+inv (R7/R12-proven). 8 blocks/graph own dst-ranges.
__global__ __launch_bounds__(TPB) void cntinv_kernel(const int* __restrict__ edge_index,
                                                     const int* __restrict__ edge_type,
                                                     float* __restrict__ inv) {
    int b = blockIdx.x, sub = blockIdx.y;
    int s0 = sub * NPS;
    __shared__ int loc[NPS * Rn];                 // 39 KB
    for (int i = threadIdx.x; i < NPS * Rn; i += TPB) loc[i] = 0;
    __syncthreads();
    const int4* dst4 = (const int4*)(edge_index + (b * 2 + 1) * En);
    const int4* et4  = (const int4*)(edge_type + b * En);
    for (int q = threadIdx.x; q < EQ; q += TPB) {
        int4 d = dst4[q]; int4 t = et4[q]; int x;
        x = d.x - s0; if ((unsigned)x < NPS) atomicAdd(&loc[x * Rn + t.x], 1);
        x = d.y - s0; if ((unsigned)x < NPS) atomicAdd(&loc[x * Rn + t.y], 1);
        x = d.z - s0; if ((unsigned)x < NPS) atomicAdd(&loc[x * Rn + t.z], 1);
        x = d.w - s0; if ((unsigned)x < NPS) atomicAdd(&loc[x * Rn + t.w], 1);
    }
    __syncthreads();
    float* ivb = inv + (size_t)b * En;
    for (int q = threadIdx.x; q < EQ; q += TPB) {
        int4 d = dst4[q]; int4 t = et4[q];
        int e = 4 * q, x;
        x = d.x - s0; if ((unsigned)x < NPS) ivb[e]     = 1.0f / (float)loc[x * Rn + t.x];
        x = d.y - s0; if ((unsigned)x < NPS) ivb[e + 1] = 1.0f / (float)loc[x * Rn + t.y];
        x = d.z - s0; if ((unsigned)x < NPS) ivb[e + 2] = 1.0f / (float)loc[x * Rn + t.z];
        x = d.w - s0; if ((unsigned)x < NPS) ivb[e + 3] = 1.0f / (float)loc[x * Rn + t.w];
    }
}

// K2: fused a+gather. Block (b,sub) owns src-range [s0,s0+250):
//   phase A: streaming edge scan, ONE LDS atomic/edge into s[src][t]
//            (stride 39, coprime to 32 banks);
//   phase B: w_loc[250][9] = s @ comp (+1.0 self column) in LDS;
//   phase C: 16 waves gather the 250 nodes' embedding rows (unroll-4),
//            weights read from LDS (broadcast), write own partial chunk.
// No global a array, no extra dispatch boundary. Also zeroes mvn tickets.
__global__ __launch_bounds__(TPB) void ag_kernel(const int* __restrict__ node_ids,
                                                 const int* __restrict__ edge_index,
                                                 const int* __restrict__ edge_type,
                                                 const float* __restrict__ inv,
                                                 const float* __restrict__ comp,
                                                 const float* __restrict__ emb,
                                                 float* __restrict__ partial,
                                                 int* __restrict__ ticket) {
    int b = blockIdx.x, sub = blockIdx.y;
    int tid = threadIdx.x;
    if (sub == 0 && tid == 0) ticket[b] = 0;      // for K3 (stream-ordered)
    int s0 = sub * NPS;
    __shared__ float s[NPS * Rn];                 // 39,000 B
    __shared__ float comp_l[Rn * Kn];             //  1,248 B
    __shared__ float w_loc[NPS * 9];              //  9,000 B
    for (int i = tid; i < NPS * Rn; i += TPB) s[i] = 0.0f;
    if (tid < Rn * Kn) comp_l[tid] = comp[tid];
    __syncthreads();
    const int4*   src4 = (const int4*)(edge_index + (b * 2 + 0) * En);
    const int4*   et4  = (const int4*)(edge_type + b * En);
    const float4* iv4  = (const float4*)(inv + (size_t)b * En);
    for (int q = tid; q < EQ; q += TPB) {
        int4 sv = src4[q]; int4 tv = et4[q]; float4 iv = iv4[q]; int x;
        x = sv.x - s0; if ((unsigned)x < NPS) atomicAdd(&s[x * Rn + tv.x], iv.x);
        x = sv.y - s0; if ((unsigned)x < NPS) atomicAdd(&s[x * Rn + tv.y], iv.y);
        x = sv.z - s0; if ((unsigned)x < NPS) atomicAdd(&s[x * Rn + tv.z], iv.z);
        x = sv.w - s0; if ((unsigned)x < NPS) atomicAdd(&s[x * Rn + tv.w], iv.w);
    }
    __syncthreads();
    for (int i = tid; i < NPS * Kn; i += TPB) {   // 2000 dots, 39 MACs each
        int n = i >> 3, k = i & 7;
        float acc = 0.0f;
        const float* srow = &s[n * Rn];
        for (int t = 0; t < Rn; t++) acc += srow[t] * comp_l[t * Kn + k];
        w_loc[n * 9 + k] = acc;
    }
    for (int i = tid; i < NPS; i += TPB) w_loc[i * 9 + 8] = 1.0f;
    __syncthreads();

    // phase C: gather. wave wv owns local nodes {l : l mod 16 == wv}
    int lane = tid & 63, wv = tid >> 6;
    float acc[18];
#pragma unroll
    for (int k = 0; k < 18; k++) acc[k] = 0.0f;
    const int* nb = node_ids + b * Nn;
    for (int l0 = wv; l0 < NPS; l0 += 4 * GW) {
        bool   has[4];
        int    ll[4];
        float2 v[4];
#pragma unroll
        for (int i = 0; i < 4; i++) {
            int l = l0 + i * GW;
            has[i] = l < NPS;
            ll[i]  = has[i] ? l : l0;
        }
#pragma unroll
        for (int i = 0; i < 4; i++) {             // batch the long-latency loads
            int nid = nb[s0 + ll[i]];
            v[i] = has[i] ? ((const float2*)(emb + (size_t)nid * Dn))[lane]
                          : make_float2(0.f, 0.f);
        }
#pragma unroll
        for (int i = 0; i < 4; i++) {
            const float* w = &w_loc[ll[i] * 9];   // LDS broadcast reads
#pragma unroll
            for (int k = 0; k < 9; k++) {
                acc[2 * k]     += w[k] * v[i].x;
                acc[2 * k + 1] += w[k] * v[i].y;
            }
        }
    }
    int W = sub * GW + wv;                        // chunk id in [0, WPG)
    float2* gp = (float2*)(partial + ((size_t)b * WPG + W) * 9 * Dn);
#pragma unroll
    for (int k = 0; k < 9; k++)
        gp[k * 64 + lane] = make_float2(acc[2 * k], acc[2 * k + 1]);
}

// K3: matvec + ticket-gated norm. One block per (graph, matrix m): reduce 128
// chunks (d-coalesced, unroll-4 ILP), matvec, write gmat, fence+ticket; the
// last-arriving block of each graph (old%9==8, replay-idempotent) does the
// ~2us norm tail on the L2-hot gmat.
__global__ __launch_bounds__(256) void mvn_kernel(const float* __restrict__ partial,
                                                  const float* __restrict__ root,
                                                  const float* __restrict__ bases,
                                                  const float* __restrict__ bias,
                                                  float* gmat,
                                                  int* ticket,
                                                  float* __restrict__ out) {
    int b = blockIdx.x, m = blockIdx.y;
    int d = threadIdx.x & (Dn - 1), h = threadIdx.x >> 7;
    __shared__ float ts[Dn];
    __shared__ float tsh[2][Dn];
    __shared__ int isLast;
    const float* p = partial + (size_t)b * WPG * 9 * Dn + m * Dn + d;
    float s0 = 0.f, s1 = 0.f, s2 = 0.f, s3 = 0.f;
    for (int c = h; c < WPG; c += 8) {            // 16 iters x 4 accumulators
        s0 += p[(size_t)(c    ) * 9 * Dn];
        s1 += p[(size_t)(c + 2) * 9 * Dn];
        s2 += p[(size_t)(c + 4) * 9 * Dn];
        s3 += p[(size_t)(c + 6) * 9 * Dn];
    }
    tsh[h][d] = (s0 + s1) + (s2 + s3);
    __syncthreads();
    if (h == 0) ts[d] = tsh[0][d] + tsh[1][d];
    __syncthreads();
    const float* M = (m == 8) ? root : bases + (size_t)m * Dn * Dn;
    float g = 0.0f;
    for (int j = h * 64; j < h * 64 + 64; j++) g += ts[j] * M[j * Dn + d];
    __syncthreads();
    tsh[h][d] = g;
    __syncthreads();
    if (h == 0) gmat[((size_t)b * 9 + m) * Dn + d] = tsh[0][d] + tsh[1][d];
    __threadfence();                              // publish gmat (release)
    if (threadIdx.x == 0) {
        int old = atomicAdd(&ticket[b], 1);
        isLast = ((old % 9) == 8);                // replay-idempotent
    }
    __syncthreads();
    if (!isLast) return;                          // non-blocking
    __threadfence();                              // acquire side

    float gg = 0.0f;
    if (threadIdx.x < Dn) {
        gg = (float)Nn * bias[d];
        const float* gb = gmat + (size_t)b * 9 * Dn + d;
#pragma unroll
        for (int mm = 0; mm < 9; mm++) gg += gb[mm * Dn];
        ts[d] = gg;
    }
    float ss = (threadIdx.x < Dn) ? gg * gg : 0.0f;
#pragma unroll
    for (int off = 32; off > 0; off >>= 1) ss += __shfl_down(ss, off, 64);
    if ((threadIdx.x & 63) == 0) tsh[0][threadIdx.x >> 6] = ss;
    __syncthreads();
    if (threadIdx.x < Dn) {
        float nrm = sqrtf(tsh[0][0] + tsh[0][1]);
        out[b * Dn + d] = ts[d] / fmaxf(nrm, 1e-5f);
    }
}

extern "C" void kernel_launch(void* const* d_in, const int* in_sizes, int n_in,
                              void* d_out, int out_size, void* d_ws, size_t ws_size,
                              hipStream_t stream) {
    const int*   node_ids   = (const int*)d_in[0];
    const int*   edge_index = (const int*)d_in[1];
    const int*   edge_type  = (const int*)d_in[2];
    const float* embedding  = (const float*)d_in[3];
    const float* bases      = (const float*)d_in[4];
    const float* comp       = (const float*)d_in[5];
    const float* root       = (const float*)d_in[6];
    const float* bias       = (const float*)d_in[7];
    float*       out        = (float*)d_out;

    char* w = (char*)d_ws;
    float* inv     = (float*)(w + 0);
    float* partial = (float*)(w + 4096000);
    float* gmat    = (float*)(w + 22970368);
    int*   ticket  = (int*)  (w + 23117824);

    cntinv_kernel<<<dim3(Bn, SUBS), TPB, 0, stream>>>(edge_index, edge_type, inv);
    ag_kernel    <<<dim3(Bn, SUBS), TPB, 0, stream>>>(node_ids, edge_index, edge_type,
                                                      inv, comp, embedding, partial, ticket);
    mvn_kernel   <<<dim3(Bn, 9),    256, 0, stream>>>(partial, root, bases, bias,
                                                      gmat, ticket, out);
}

// Round 15
// 149.329 us; speedup vs baseline: 1.1096x; 1.1096x over previous
//
#include <hip/hip_runtime.h>
#include <math.h>

#define Bn 32
#define Nn 2000
#define En 32000
#define Vn 100000
#define Dn 128
#define Rn 39
#define Kn 8

#define SUBS 8
#define NPS (Nn / SUBS)   // 250 nodes per sub-block
#define WPG 128           // gather waves (= partial chunks) per graph
#define EQ (En / 4)       // 8000 edge-quads per graph
#define NR (NPS * Rn)     // 9750 LDS cells per sub-block

// Workspace layout (no aliasing):
//   [ 0)          : inv     float[B*E]          =  4,096,000
//   [ 4,096,000)  : a       float[B*N*K]        =  2,048,000
//   [ 6,144,000)  : partial float[B*9*WPG*128]  = 18,874,368   ([b][k][W][d])
//   [25,018,368)  : gmat    float[B*9*128]      =    147,456
//
// R14 = R12 shape (proven 156us; 3-dispatch fusions measured SLOWER) + micro:
// fused mad-filter in scans, gather unroll-8, streaming matvec reduce.
// blockIdx.x = graph everywhere -> XCD affinity (R2 evidence: 9x fetch cut).

// K1: fused cnt+inv. 8 blocks/graph own dst-ranges. Fused filter:
// y = dst*39+et - s0*39; in-range iff (unsigned)y < 9750 (ranges don't overlap
// since dst*39+et is monotone in dst and et<39).
__global__ __launch_bounds__(1024) void cntinv_kernel(const int* __restrict__ edge_index,
                                                      const int* __restrict__ edge_type,
                                                      float* __restrict__ inv) {
    int b = blockIdx.x, sub = blockIdx.y;
    int base = sub * NR;
    __shared__ int loc[NR];                       // 39 KB
    for (int i = threadIdx.x; i < NR; i += 1024) loc[i] = 0;
    __syncthreads();
    const int4* dst4 = (const int4*)(edge_index + (b * 2 + 1) * En);
    const int4* et4  = (const int4*)(edge_type + b * En);
    for (int q = threadIdx.x; q < EQ; q += 1024) {
        int4 d = dst4[q]; int4 t = et4[q]; int y;
        y = d.x * Rn + t.x - base; if ((unsigned)y < NR) atomicAdd(&loc[y], 1);
        y = d.y * Rn + t.y - base; if ((unsigned)y < NR) atomicAdd(&loc[y], 1);
        y = d.z * Rn + t.z - base; if ((unsigned)y < NR) atomicAdd(&loc[y], 1);
        y = d.w * Rn + t.w - base; if ((unsigned)y < NR) atomicAdd(&loc[y], 1);
    }
    __syncthreads();
    float* ivb = inv + (size_t)b * En;
    for (int q = threadIdx.x; q < EQ; q += 1024) {
        int4 d = dst4[q]; int4 t = et4[q];
        int e = 4 * q, y;
        y = d.x * Rn + t.x - base; if ((unsigned)y < NR) ivb[e]     = 1.0f / (float)loc[y];
        y = d.y * Rn + t.y - base; if ((unsigned)y < NR) ivb[e + 1] = 1.0f / (float)loc[y];
        y = d.z * Rn + t.z - base; if ((unsigned)y < NR) ivb[e + 2] = 1.0f / (float)loc[y];
        y = d.w * Rn + t.w - base; if ((unsigned)y < NR) ivb[e + 3] = 1.0f / (float)loc[y];
    }
}

// K2: 8 blocks/graph own src-ranges. Streaming scan, fused mad-filter, ONE LDS
// atomic/edge into s[src*39+t] (stride 39, coprime to 32 banks), then
// a[n][k] = s @ comp.
__global__ __launch_bounds__(1024) void a_kernel(const int* __restrict__ edge_index,
                                                 const int* __restrict__ edge_type,
                                                 const float* __restrict__ inv,
                                                 const float* __restrict__ comp,
                                                 float* __restrict__ a) {
    int b = blockIdx.x, sub = blockIdx.y;
    int base = sub * NR;
    __shared__ float s[NR];                       // 39 KB
    __shared__ float comp_l[Rn * Kn];
    for (int i = threadIdx.x; i < NR; i += 1024) s[i] = 0.0f;
    if (threadIdx.x < Rn * Kn) comp_l[threadIdx.x] = comp[threadIdx.x];
    __syncthreads();
    const int4*   src4 = (const int4*)(edge_index + (b * 2 + 0) * En);
    const int4*   et4  = (const int4*)(edge_type + b * En);
    const float4* iv4  = (const float4*)(inv + (size_t)b * En);
    for (int q = threadIdx.x; q < EQ; q += 1024) {
        int4 sv = src4[q]; int4 tv = et4[q]; float4 iv = iv4[q]; int y;
        y = sv.x * Rn + tv.x - base; if ((unsigned)y < NR) atomicAdd(&s[y], iv.x);
        y = sv.y * Rn + tv.y - base; if ((unsigned)y < NR) atomicAdd(&s[y], iv.y);
        y = sv.z * Rn + tv.z - base; if ((unsigned)y < NR) atomicAdd(&s[y], iv.z);
        y = sv.w * Rn + tv.w - base; if ((unsigned)y < NR) atomicAdd(&s[y], iv.w);
    }
    __syncthreads();
    float* g = a + ((size_t)b * Nn + sub * NPS) * Kn;
    for (int i = threadIdx.x; i < NPS * Kn; i += 1024) {   // 2000 outputs
        int n = i >> 3, k = i & 7;
        float acc = 0.0f;
        const float* srow = &s[n * Rn];
        for (int t = 0; t < Rn; t++) acc += srow[t] * comp_l[t * Kn + k];
        g[i] = acc;
    }
}

// K3: wave-autonomous gather, unroll-8 (8 independent 512B row loads in
// flight). Each of 128 waves/graph owns {n : n mod 128 == W} (~16 nodes).
// Stores to partial[b][k][W][d] — 512B-coalesced per (k,W).
__global__ __launch_bounds__(256) void gather_kernel(const int* __restrict__ node_ids,
                                                     const float* __restrict__ emb,
                                                     const float* __restrict__ a,
                                                     float* __restrict__ partial) {
    int b = blockIdx.x;
    int lane = threadIdx.x & 63, wv = threadIdx.x >> 6;
    int W = blockIdx.y * 4 + wv;                  // wave id in [0, WPG)
    float acc[18];
#pragma unroll
    for (int k = 0; k < 18; k++) acc[k] = 0.0f;
    const int*   nb = node_ids + b * Nn;
    const float* ab = a + (size_t)b * Nn * Kn;
    for (int n0 = W; n0 < Nn; n0 += 8 * WPG) {    // 2 outer iters (Nn=2000)
        bool   has[8];
        int    nn[8];
        float2 v[8];
        float4 a0[8], a1[8];
#pragma unroll
        for (int i = 0; i < 8; i++) {
            int n = n0 + i * WPG;
            has[i] = n < Nn;
            nn[i]  = has[i] ? n : n0;
        }
#pragma unroll
        for (int i = 0; i < 8; i++) {             // 8 long-latency loads batched
            int nid = nb[nn[i]];
            v[i] = has[i] ? ((const float2*)(emb + (size_t)nid * Dn))[lane]
                          : make_float2(0.f, 0.f);
            const float4* ar = (const float4*)(ab + (size_t)nn[i] * Kn);
            a0[i] = ar[0]; a1[i] = ar[1];
        }
#pragma unroll
        for (int i = 0; i < 8; i++) {
            float w[9] = {a0[i].x, a0[i].y, a0[i].z, a0[i].w,
                          a1[i].x, a1[i].y, a1[i].z, a1[i].w, 1.0f};
#pragma unroll
            for (int k = 0; k < 9; k++) {
                acc[2 * k]     += w[k] * v[i].x;
                acc[2 * k + 1] += w[k] * v[i].y;
            }
        }
    }
#pragma unroll
    for (int k = 0; k < 9; k++) {
        float2* gp = (float2*)(partial + (((size_t)b * 9 + k) * WPG + W) * Dn);
        gp[lane] = make_float2(acc[2 * k], acc[2 * k + 1]);
    }
}

// K4: one block per (graph, matrix m). Reduce over W is now a CONTIGUOUS
// 64 KB float4 stream ([m] slab of partial). Then matvec, write gmat.
__global__ __launch_bounds__(256) void matvec_kernel(const float* __restrict__ partial,
                                                     const float* __restrict__ root,
                                                     const float* __restrict__ bases,
                                                     float* __restrict__ gmat) {
    int b = blockIdx.x, m = blockIdx.y;
    int tid = threadIdx.x;
    __shared__ float4 ts4[Dn / 4];                // ts[128] as 32 float4
    __shared__ float tsh[8][Dn];                  // per-part sums (8*128*4B)
    int dg = tid & 31, part = tid >> 5;           // 32 d-groups x 8 W-parts
    const float4* p4 = (const float4*)(partial + ((size_t)b * 9 + m) * WPG * Dn);
    float4 sum = make_float4(0.f, 0.f, 0.f, 0.f);
    for (int c = part; c < WPG; c += 8) {         // 16 iters, contiguous stream
        float4 v = p4[c * 32 + dg];
        sum.x += v.x; sum.y += v.y; sum.z += v.z; sum.w += v.w;
    }
    ((float4*)tsh[part])[dg] = sum;
    __syncthreads();
    if (part == 0) {
        float4 t = make_float4(0.f, 0.f, 0.f, 0.f);
#pragma unroll
        for (int r = 0; r < 8; r++) {
            float4 v = ((float4*)tsh[r])[dg];
            t.x += v.x; t.y += v.y; t.z += v.z; t.w += v.w;
        }
        ts4[dg] = t;
    }
    __syncthreads();
    const float* ts = (const float*)ts4;
    const float* M  = (m == 8) ? root : bases + (size_t)m * Dn * Dn;
    int d = tid & (Dn - 1), h = tid >> 7;
    float g = 0.0f;
    for (int j = h * 64; j < h * 64 + 64; j++) g += ts[j] * M[j * Dn + d];
    __syncthreads();
    tsh[0][d + h * 0] = 0.0f;                     // (avoid bank clash writes below)
    __syncthreads();
    tsh[h][d] = g;
    __syncthreads();
    if (h == 0) gmat[((size_t)b * 9 + m) * Dn + d] = tsh[0][d] + tsh[1][d];
}

// K5: sum the 9 matvec outputs, add bias term, L2-normalize.
__global__ __launch_bounds__(128) void norm_kernel(const float* __restrict__ gmat,
                                                   const float* __restrict__ bias,
                                                   float* __restrict__ out) {
    int b = blockIdx.x, d = threadIdx.x;
    float g = (float)Nn * bias[d];
    const float* gb = gmat + (size_t)b * 9 * Dn + d;
#pragma unroll
    for (int m = 0; m < 9; m++) g += gb[m * Dn];
    float ss = g * g;
#pragma unroll
    for (int off = 32; off > 0; off >>= 1) ss += __shfl_down(ss, off, 64);
    __shared__ float s2[2];
    if ((threadIdx.x & 63) == 0) s2[threadIdx.x >> 6] = ss;
    __syncthreads();
    float nrm = sqrtf(s2[0] + s2[1]);
    out[b * Dn + d] = g / fmaxf(nrm, 1e-5f);
}

extern "C" void kernel_launch(void* const* d_in, const int* in_sizes, int n_in,
                              void* d_out, int out_size, void* d_ws, size_t ws_size,
                              hipStream_t stream) {
    const int*   node_ids   = (const int*)d_in[0];
    const int*   edge_index = (const int*)d_in[1];
    const int*   edge_type  = (const int*)d_in[2];
    const float* embedding  = (const float*)d_in[3];
    const float* bases      = (const float*)d_in[4];
    const float* comp       = (const float*)d_in[5];
    const float* root       = (const float*)d_in[6];
    const float* bias       = (const float*)d_in[7];
    float*       out        = (float*)d_out;

    char* w = (char*)d_ws;
    float* inv     = (float*)(w + 0);
    float* a       = (float*)(w + 4096000);
    float* partial = (float*)(w + 6144000);
    float* gmat    = (float*)(w + 25018368);

    cntinv_kernel<<<dim3(Bn, SUBS),    1024, 0, stream>>>(edge_index, edge_type, inv);
    a_kernel     <<<dim3(Bn, SUBS),    1024, 0, stream>>>(edge_index, edge_type, inv, comp, a);
    gather_kernel<<<dim3(Bn, WPG / 4), 256,  0, stream>>>(node_ids, embedding, a, partial);
    matvec_kernel<<<dim3(Bn, 9),       256,  0, stream>>>(partial, root, bases, gmat);
    norm_kernel  <<<Bn, 128, 0, stream>>>(gmat, bias, out);
}

// Round 16
// 146.229 us; speedup vs baseline: 1.1331x; 1.0212x over previous
//
#include <hip/hip_runtime.h>
#include <math.h>

#define Bn 32
#define Nn 2000
#define En 32000
#define Vn 100000
#define Dn 128
#define Rn 39
#define Kn 8

#define SUBS 8
#define NPS (Nn / SUBS)   // 250 nodes per sub-block
#define WPG 64            // gather waves per graph (each handles node PAIRS)
#define NPAIR (Nn / 2)    // 1000 node pairs per graph
#define EQ (En / 4)       // 8000 edge-quads per graph
#define NR (NPS * Rn)     // 9750 LDS cells per sub-block

// Workspace layout (no aliasing):
//   [ 0)          : inv     float[B*E]          =  4,096,000
//   [ 4,096,000)  : a       float[B*N*K]        =  2,048,000
//   [ 6,144,000)  : partial float[B*9*WPG*128]  =  9,437,184   ([b][k][W][d])
//   [15,581,184)  : gmat    float[B*9*128]      =    147,456
//
// R15 = R14 (proven 149.3us) + gather node-pairing: float4/lane -> one wave
// instruction covers TWO embedding rows; WPG 128->64; partial halves to
// 9.4MB so matvec reduce stream halves too.
// blockIdx.x = graph everywhere -> XCD affinity (R2 evidence: 9x fetch cut).

// K1: fused cnt+inv. 8 blocks/graph own dst-ranges. Fused mad-filter:
// y = dst*39+et - sub*9750; in-range iff (unsigned)y < 9750.
__global__ __launch_bounds__(1024) void cntinv_kernel(const int* __restrict__ edge_index,
                                                      const int* __restrict__ edge_type,
                                                      float* __restrict__ inv) {
    int b = blockIdx.x, sub = blockIdx.y;
    int base = sub * NR;
    __shared__ int loc[NR];                       // 39 KB
    for (int i = threadIdx.x; i < NR; i += 1024) loc[i] = 0;
    __syncthreads();
    const int4* dst4 = (const int4*)(edge_index + (b * 2 + 1) * En);
    const int4* et4  = (const int4*)(edge_type + b * En);
    for (int q = threadIdx.x; q < EQ; q += 1024) {
        int4 d = dst4[q]; int4 t = et4[q]; int y;
        y = d.x * Rn + t.x - base; if ((unsigned)y < NR) atomicAdd(&loc[y], 1);
        y = d.y * Rn + t.y - base; if ((unsigned)y < NR) atomicAdd(&loc[y], 1);
        y = d.z * Rn + t.z - base; if ((unsigned)y < NR) atomicAdd(&loc[y], 1);
        y = d.w * Rn + t.w - base; if ((unsigned)y < NR) atomicAdd(&loc[y], 1);
    }
    __syncthreads();
    float* ivb = inv + (size_t)b * En;
    for (int q = threadIdx.x; q < EQ; q += 1024) {
        int4 d = dst4[q]; int4 t = et4[q];
        int e = 4 * q, y;
        y = d.x * Rn + t.x - base; if ((unsigned)y < NR) ivb[e]     = 1.0f / (float)loc[y];
        y = d.y * Rn + t.y - base; if ((unsigned)y < NR) ivb[e + 1] = 1.0f / (float)loc[y];
        y = d.z * Rn + t.z - base; if ((unsigned)y < NR) ivb[e + 2] = 1.0f / (float)loc[y];
        y = d.w * Rn + t.w - base; if ((unsigned)y < NR) ivb[e + 3] = 1.0f / (float)loc[y];
    }
}

// K2: 8 blocks/graph own src-ranges. Streaming scan, fused mad-filter, ONE LDS
// atomic/edge into s[src*39+t] (stride 39, coprime to 32 banks), then
// a[n][k] = s @ comp.
__global__ __launch_bounds__(1024) void a_kernel(const int* __restrict__ edge_index,
                                                 const int* __restrict__ edge_type,
                                                 const float* __restrict__ inv,
                                                 const float* __restrict__ comp,
                                                 float* __restrict__ a) {
    int b = blockIdx.x, sub = blockIdx.y;
    int base = sub * NR;
    __shared__ float s[NR];                       // 39 KB
    __shared__ float comp_l[Rn * Kn];
    for (int i = threadIdx.x; i < NR; i += 1024) s[i] = 0.0f;
    if (threadIdx.x < Rn * Kn) comp_l[threadIdx.x] = comp[threadIdx.x];
    __syncthreads();
    const int4*   src4 = (const int4*)(edge_index + (b * 2 + 0) * En);
    const int4*   et4  = (const int4*)(edge_type + b * En);
    const float4* iv4  = (const float4*)(inv + (size_t)b * En);
    for (int q = threadIdx.x; q < EQ; q += 1024) {
        int4 sv = src4[q]; int4 tv = et4[q]; float4 iv = iv4[q]; int y;
        y = sv.x * Rn + tv.x - base; if ((unsigned)y < NR) atomicAdd(&s[y], iv.x);
        y = sv.y * Rn + tv.y - base; if ((unsigned)y < NR) atomicAdd(&s[y], iv.y);
        y = sv.z * Rn + tv.z - base; if ((unsigned)y < NR) atomicAdd(&s[y], iv.z);
        y = sv.w * Rn + tv.w - base; if ((unsigned)y < NR) atomicAdd(&s[y], iv.w);
    }
    __syncthreads();
    float* g = a + ((size_t)b * Nn + sub * NPS) * Kn;
    for (int i = threadIdx.x; i < NPS * Kn; i += 1024) {   // 2000 outputs
        int n = i >> 3, k = i & 7;
        float acc = 0.0f;
        const float* srow = &s[n * Rn];
        for (int t = 0; t < Rn; t++) acc += srow[t] * comp_l[t * Kn + k];
        g[i] = acc;
    }
}

// K3: paired gather. Wave W owns node pairs {p : p mod 64 == W}; lanes 0-31
// cover node 2p (d = 4*(lane&31)..+3 via float4), lanes 32-63 cover node 2p+1.
// Batch-8 pairs (8 KB in flight/wave). Half-wave accumulators merged by
// shfl(+32); lanes 0-31 store 512B-coalesced to partial[b][k][W][d].
__global__ __launch_bounds__(256) void gather_kernel(const int* __restrict__ node_ids,
                                                     const float* __restrict__ emb,
                                                     const float* __restrict__ a,
                                                     float* __restrict__ partial) {
    int b = blockIdx.x;
    int lane = threadIdx.x & 63, wv = threadIdx.x >> 6;
    int W = blockIdx.y * 4 + wv;                  // wave id in [0, WPG)
    int half = lane >> 5;                         // 0: even node, 1: odd node
    int dl = lane & 31;                           // float4 slot: d = 4*dl..4*dl+3
    float4 acc[9];
#pragma unroll
    for (int k = 0; k < 9; k++) acc[k] = make_float4(0.f, 0.f, 0.f, 0.f);
    const int*   nb = node_ids + b * Nn;
    const float* ab = a + (size_t)b * Nn * Kn;
    for (int p0 = W; p0 < NPAIR; p0 += 8 * WPG) { // 2 outer iters
        bool   has[8];
        int    node[8];
        float4 v[8];
        float4 a0[8], a1[8];
#pragma unroll
        for (int i = 0; i < 8; i++) {
            int p = p0 + i * WPG;
            has[i] = p < NPAIR;
            node[i] = (has[i] ? 2 * p : 0) + half;
        }
#pragma unroll
        for (int i = 0; i < 8; i++) {             // 8 batched 1KB row loads
            int nid = nb[node[i]];
            v[i] = has[i] ? ((const float4*)(emb + (size_t)nid * Dn))[dl]
                          : make_float4(0.f, 0.f, 0.f, 0.f);
            const float4* ar = (const float4*)(ab + (size_t)node[i] * Kn);
            a0[i] = ar[0]; a1[i] = ar[1];
        }
#pragma unroll
        for (int i = 0; i < 8; i++) {
            float w[9] = {a0[i].x, a0[i].y, a0[i].z, a0[i].w,
                          a1[i].x, a1[i].y, a1[i].z, a1[i].w, 1.0f};
#pragma unroll
            for (int k = 0; k < 9; k++) {
                acc[k].x += w[k] * v[i].x;
                acc[k].y += w[k] * v[i].y;
                acc[k].z += w[k] * v[i].z;
                acc[k].w += w[k] * v[i].w;
            }
        }
    }
    // merge odd-node half into even half (same d-range), store coalesced
#pragma unroll
    for (int k = 0; k < 9; k++) {
        acc[k].x += __shfl_down(acc[k].x, 32, 64);
        acc[k].y += __shfl_down(acc[k].y, 32, 64);
        acc[k].z += __shfl_down(acc[k].z, 32, 64);
        acc[k].w += __shfl_down(acc[k].w, 32, 64);
    }
    if (half == 0) {
#pragma unroll
        for (int k = 0; k < 9; k++) {
            float4* gp = (float4*)(partial + (((size_t)b * 9 + k) * WPG + W) * Dn);
            gp[dl] = acc[k];
        }
    }
}

// K4: one block per (graph, matrix m). Reduce over W is a CONTIGUOUS 32 KB
// float4 stream ([m] slab of partial). Then matvec, write gmat.
__global__ __launch_bounds__(256) void matvec_kernel(const float* __restrict__ partial,
                                                     const float* __restrict__ root,
                                                     const float* __restrict__ bases,
                                                     float* __restrict__ gmat) {
    int b = blockIdx.x, m = blockIdx.y;
    int tid = threadIdx.x;
    __shared__ float4 ts4[Dn / 4];                // ts[128] as 32 float4
    __shared__ float tsh[8][Dn];
    int dg = tid & 31, part = tid >> 5;           // 32 d-groups x 8 W-parts
    const float4* p4 = (const float4*)(partial + ((size_t)b * 9 + m) * WPG * Dn);
    float4 sum = make_float4(0.f, 0.f, 0.f, 0.f);
    for (int c = part; c < WPG; c += 8) {         // 8 iters, contiguous stream
        float4 v = p4[c * 32 + dg];
        sum.x += v.x; sum.y += v.y; sum.z += v.z; sum.w += v.w;
    }
    ((float4*)tsh[part])[dg] = sum;
    __syncthreads();
    if (part == 0) {
        float4 t = make_float4(0.f, 0.f, 0.f, 0.f);
#pragma unroll
        for (int r = 0; r < 8; r++) {
            float4 v = ((float4*)tsh[r])[dg];
            t.x += v.x; t.y += v.y; t.z += v.z; t.w += v.w;
        }
        ts4[dg] = t;
    }
    __syncthreads();
    const float* ts = (const float*)ts4;
    const float* M  = (m == 8) ? root : bases + (size_t)m * Dn * Dn;
    int d = tid & (Dn - 1), h = tid >> 7;
    float g = 0.0f;
    for (int j = h * 64; j < h * 64 + 64; j++) g += ts[j] * M[j * Dn + d];
    __syncthreads();
    tsh[h][d] = g;
    __syncthreads();
    if (h == 0) gmat[((size_t)b * 9 + m) * Dn + d] = tsh[0][d] + tsh[1][d];
}

// K5: sum the 9 matvec outputs, add bias term, L2-normalize.
__global__ __launch_bounds__(128) void norm_kernel(const float* __restrict__ gmat,
                                                   const float* __restrict__ bias,
                                                   float* __restrict__ out) {
    int b = blockIdx.x, d = threadIdx.x;
    float g = (float)Nn * bias[d];
    const float* gb = gmat + (size_t)b * 9 * Dn + d;
#pragma unroll
    for (int m = 0; m < 9; m++) g += gb[m * Dn];
    float ss = g * g;
#pragma unroll
    for (int off = 32; off > 0; off >>= 1) ss += __shfl_down(ss, off, 64);
    __shared__ float s2[2];
    if ((threadIdx.x & 63) == 0) s2[threadIdx.x >> 6] = ss;
    __syncthreads();
    float nrm = sqrtf(s2[0] + s2[1]);
    out[b * Dn + d] = g / fmaxf(nrm, 1e-5f);
}

extern "C" void kernel_launch(void* const* d_in, const int* in_sizes, int n_in,
                              void* d_out, int out_size, void* d_ws, size_t ws_size,
                              hipStream_t stream) {
    const int*   node_ids   = (const int*)d_in[0];
    const int*   edge_index = (const int*)d_in[1];
    const int*   edge_type  = (const int*)d_in[2];
    const float* embedding  = (const float*)d_in[3];
    const float* bases      = (const float*)d_in[4];
    const float* comp       = (const float*)d_in[5];
    const float* root       = (const float*)d_in[6];
    const float* bias       = (const float*)d_in[7];
    float*       out        = (float*)d_out;

    char* w = (char*)d_ws;
    float* inv     = (float*)(w + 0);
    float* a       = (float*)(w + 4096000);
    float* partial = (float*)(w + 6144000);
    float* gmat    = (float*)(w + 15581184);

    cntinv_kernel<<<dim3(Bn, SUBS),    1024, 0, stream>>>(edge_index, edge_type, inv);
    a_kernel     <<<dim3(Bn, SUBS),    1024, 0, stream>>>(edge_index, edge_type, inv, comp, a);
    gather_kernel<<<dim3(Bn, WPG / 4), 256,  0, stream>>>(node_ids, embedding, a, partial);
    matvec_kernel<<<dim3(Bn, 9),       256,  0, stream>>>(partial, root, bases, gmat);
    norm_kernel  <<<Bn, 128, 0, stream>>>(gmat, bias, out);
}